// Round 10
// baseline (669.172 us; speedup 1.0000x reference)
//
#include <hip/hip_runtime.h>
#include <hip/hip_bf16.h>

// LSTM: B=512, T=4096, I=1, H=16, O=1. f32 in/out.
// R9: TLP — 8 waves per block (512 thr), grid=64 -> 2 waves per SIMD.
// HW wave interleaving fills each chain's stall cycles with the co-resident
// wave's issue (what R2's single-wave dual-chain could not achieve).
// Step body = exact R4 (best known-good): f16 packed dot (8x v_dot2_f32_f16),
// 2 accumulator chains, unroll-16 windows, branchy prefetch, asm trans.
// FC tile shrunk to 16 rows/wave (33 KB total LDS), flushed every 16 steps
// via quad-reduction. Full-64-unroll RETIRED (R5/R6 corruption).

constexpr int NB  = 512;   // batch
constexpr int NT  = 4096;  // timesteps
constexpr int WPB = 8;     // waves per block (2 per SIMD)

typedef _Float16 half2_t __attribute__((ext_vector_type(2)));
typedef __fp16   fp16v2  __attribute__((ext_vector_type(2)));

template<int CTRL>
__device__ __forceinline__ float qbcast(float x) {
  return __int_as_float(__builtin_amdgcn_mov_dpp(__float_as_int(x), CTRL, 0xF, 0xF, true));
}
template<int CTRL>
__device__ __forceinline__ float qperm(float x) {      // generic quad_perm
  return __int_as_float(__builtin_amdgcn_mov_dpp(__float_as_int(x), CTRL, 0xF, 0xF, true));
}
__device__ __forceinline__ float dpp_shl4(float x) {   // lane l <- lane l+4
  return __int_as_float(__builtin_amdgcn_mov_dpp(__float_as_int(x), 0x104, 0xF, 0xF, true));
}
__device__ __forceinline__ int rdlane_i(int x, int lane) {
  return __builtin_amdgcn_readlane(x, lane);
}
__device__ __forceinline__ float rdlane(float x, int lane) {
  return __int_as_float(__builtin_amdgcn_readlane(__float_as_int(x), lane));
}
__device__ __forceinline__ float vexp2(float x) {
  float r; asm("v_exp_f32 %0, %1" : "=v"(r) : "v"(x)); return r;
}
__device__ __forceinline__ float vrcp(float x) {
  float r; asm("v_rcp_f32 %0, %1" : "=v"(r) : "v"(x)); return r;
}
__device__ __forceinline__ half2_t h2_from_i(int x) {
  union { int i; half2_t h; } u; u.i = x; return u.h;
}
__device__ __forceinline__ int pack_f16(float lo, float hi) {
  union { fp16v2 v; int i; } u; u.v = __builtin_amdgcn_cvt_pkrtz(lo, hi); return u.i;
}

__global__ __launch_bounds__(512, 2) void lstm_fused(
    const float* __restrict__ x,     // [B, T]
    const float* __restrict__ W_ih,  // [64, 1]
    const float* __restrict__ W_hh,  // [64, 16]
    const float* __restrict__ b_ih,  // [64]
    const float* __restrict__ b_hh,  // [64]
    const float* __restrict__ W_fc,  // [1, 16]
    const float* __restrict__ b_fc,  // [1]
    float* __restrict__ out)         // [B, T]
{
  __shared__ float tile[WPB][16 * 65];   // per-wave 16 rows, stride 65; 33 KB
  const int wid = threadIdx.x >> 6;      // wave id in block
  const int l   = threadIdx.x & 63;
  const int b   = blockIdx.x * WPB + wid;
  const int j   = l >> 2;
  const int k   = l & 3;                 // 0=i 1=f 2=g 3=o
  const int r   = k * 16 + j;
  float* mytile = &tile[wid][0];

  constexpr float LOG2E = 1.4426950408889634f;
  constexpr float K2    = -2.0f * LOG2E;       // cs = K2 * c
  const float sc = (k == 2) ? K2 : -LOG2E;

  half2_t w2[8];
  #pragma unroll
  for (int q = 0; q < 8; ++q) {
    w2[q][0] = (_Float16)(W_hh[r * 16 + 2 * q + 0] * sc);
    w2[q][1] = (_Float16)(W_hh[r * 16 + 2 * q + 1] * sc);
  }
  const float wx    = W_ih[r] * sc;
  const float wb    = (b_ih[r] + b_hh[r]) * sc;
  const float act_m = (k == 2) ? (2.0f * K2) : 1.0f;
  const float act_a = (k == 2) ? (-K2)       : 0.0f;
  const float wfc   = W_fc[j] * 0.25f;
  const float bfc   = b_fc[0];

  const float* xb = x + (size_t)b * NT;
  float*       ob = out + (size_t)b * NT;

  float cs = 0.0f;                   // K2-scaled cell state
  int sp[8];                         // packed f16 h-pairs, wave-uniform
  #pragma unroll
  for (int q = 0; q < 8; ++q) sp[q] = 0;

  float xcur = xb[l];

  for (int blk = 0; blk < NT / 64; ++blk) {
    float xnext = 0.0f;
    if (blk + 1 < NT / 64) xnext = xb[(blk + 1) * 64 + l];  // prefetch

    #pragma unroll 1
    for (int sub = 0; sub < 4; ++sub) {      // NOT unrolled (64-unroll retired)
      const int tbase = sub * 16;

      #pragma unroll
      for (int tt = 0; tt < 16; ++tt) {      // 16-step window, like R4
        const float sx    = rdlane(xcur, tbase + tt);  // uniform x_t
        const float xinit = fmaf(wx, sx, wb);          // off-chain
        // z = xinit + sum_q w2[q].h2[q]; 2 chains of depth 4 (R4 layout)
        float a0 = __builtin_amdgcn_fdot2(w2[0], h2_from_i(sp[0]), xinit, false);
        float a1 = __builtin_amdgcn_fdot2(w2[1], h2_from_i(sp[1]), 0.0f,  false);
        #pragma unroll
        for (int q = 2; q < 8; q += 2) {
          a0 = __builtin_amdgcn_fdot2(w2[q + 0], h2_from_i(sp[q + 0]), a0, false);
          a1 = __builtin_amdgcn_fdot2(w2[q + 1], h2_from_i(sp[q + 1]), a1, false);
        }
        const float z   = a0 + a1;
        const float e1  = vexp2(z);
        const float r1  = vrcp(1.0f + e1);
        const float act = fmaf(r1, act_m, act_a);  // i/f/o: sigma; g: K2*tanh
        const float ii  = qbcast<0x00>(act);
        const float ff  = qbcast<0x55>(act);
        const float ggs = qbcast<0xAA>(act);       // K2*tanh(zg)
        const float oo  = qbcast<0xFF>(act);
        const float oo2 = oo + oo;                 // off-chain
        cs = fmaf(ff, cs, ii * ggs);               // K2-scaled cell update
        const float e2 = vexp2(cs);                // = exp(-2c)
        const float r2 = vrcp(1.0f + e2);          // = sigma(2c)
        const float h  = fmaf(oo2, r2, -oo);       // = o * tanh(c)
        mytile[tt * 65 + l] = h * wfc;             // FC partial (off-chain)
        const float hn = dpp_shl4(h);              // (h_j, h_{j+1}) pack
        const int   hi = pack_f16(h, hn);
        #pragma unroll
        for (int q = 0; q < 8; ++q) sp[q] = rdlane_i(hi, 8 * q);
      }

      // Flush 16 outputs: row = l>>2, quarter = l&3 (16 entries each),
      // then quad-reduce; lane k==0 of each quad stores.
      {
        const int row = l >> 2;
        const int q4  = l & 3;
        float s = 0.0f;
        #pragma unroll
        for (int i2 = 0; i2 < 16; ++i2)
          s += mytile[row * 65 + q4 * 16 + i2];
        s += qperm<0xB1>(s);                       // [1,0,3,2]
        s += qperm<0x4E>(s);                       // [2,3,0,1]
        if (q4 == 0) ob[blk * 64 + tbase + row] = s + bfc;
      }
    }
    xcur = xnext;
  }
}

extern "C" void kernel_launch(void* const* d_in, const int* in_sizes, int n_in,
                              void* d_out, int out_size, void* d_ws, size_t ws_size,
                              hipStream_t stream) {
  const float* x    = (const float*)d_in[0];
  const float* W_ih = (const float*)d_in[1];
  const float* W_hh = (const float*)d_in[2];
  const float* b_ih = (const float*)d_in[3];
  const float* b_hh = (const float*)d_in[4];
  const float* W_fc = (const float*)d_in[5];
  const float* b_fc = (const float*)d_in[6];
  float* out = (float*)d_out;
  (void)in_sizes; (void)n_in; (void)out_size; (void)d_ws; (void)ws_size;
  lstm_fused<<<NB / WPB, WPB * 64, 0, stream>>>(x, W_ih, W_hh, b_ih, b_hh, W_fc, b_fc, out);
}

// Round 11
// 399.560 us; speedup vs baseline: 1.6748x; 1.6748x over previous
//
#include <hip/hip_runtime.h>
#include <hip/hip_bf16.h>

// LSTM: B=512, T=4096, I=1, H=16, O=1. f32 in/out.
// One wave per batch element (512 waves, 2/CU on separate SIMDs). Lane l:
// gate k=l&3 (i,f,g,o), unit j=l>>2, row r=16k+j. f16 packed recurrent dot
// (8x v_dot2_f32_f16), h broadcast as 8 packed-f16 readlanes.
// R10 = exact R4 body (best known-good, 396us) + two unconfounded shaves:
//  (a) g-gate affine applied AFTER qbcast (bit-identical, 1 fma off the
//      pre-broadcast chain) — R8's tweak, now with asm trans;
//  (b) double-buffered FC tile (2x64x65, 33KB): removes the WAR between
//      the flush reads of window t and the tile writes of window t+1, so
//      flush instrs slide into the next window's chain stalls.
// RETIRED: full-64-unroll (R5/R6 corruption), TLP>1 wave/SIMD (R9: 2I>I+S,
// I~170-195 cyc/step from VALUBusy on active CUs), dual-chain/wave (R2),
// builtin trans (R8 neutral-negative), 4-chain dot (R7 +19us).

constexpr int NB = 512;   // batch
constexpr int NT = 4096;  // timesteps

typedef _Float16 half2_t __attribute__((ext_vector_type(2)));
typedef __fp16   fp16v2  __attribute__((ext_vector_type(2)));

template<int CTRL>
__device__ __forceinline__ float qbcast(float x) {
  return __int_as_float(__builtin_amdgcn_mov_dpp(__float_as_int(x), CTRL, 0xF, 0xF, true));
}
__device__ __forceinline__ float dpp_shl4(float x) {   // lane l <- lane l+4
  return __int_as_float(__builtin_amdgcn_mov_dpp(__float_as_int(x), 0x104, 0xF, 0xF, true));
}
__device__ __forceinline__ int rdlane_i(int x, int lane) {
  return __builtin_amdgcn_readlane(x, lane);
}
__device__ __forceinline__ float rdlane(float x, int lane) {
  return __int_as_float(__builtin_amdgcn_readlane(__float_as_int(x), lane));
}
__device__ __forceinline__ float vexp2(float x) {
  float r; asm("v_exp_f32 %0, %1" : "=v"(r) : "v"(x)); return r;
}
__device__ __forceinline__ float vrcp(float x) {
  float r; asm("v_rcp_f32 %0, %1" : "=v"(r) : "v"(x)); return r;
}
__device__ __forceinline__ half2_t h2_from_i(int x) {
  union { int i; half2_t h; } u; u.i = x; return u.h;
}
__device__ __forceinline__ int pack_f16(float lo, float hi) {
  union { fp16v2 v; int i; } u; u.v = __builtin_amdgcn_cvt_pkrtz(lo, hi); return u.i;
}

__global__ __launch_bounds__(64, 1) void lstm_fused(
    const float* __restrict__ x,     // [B, T]
    const float* __restrict__ W_ih,  // [64, 1]
    const float* __restrict__ W_hh,  // [64, 16]
    const float* __restrict__ b_ih,  // [64]
    const float* __restrict__ b_hh,  // [64]
    const float* __restrict__ W_fc,  // [1, 16]
    const float* __restrict__ b_fc,  // [1]
    float* __restrict__ out)         // [B, T]
{
  __shared__ float tile[2][64 * 65]; // double-buffered; stride 65 conflict-free
  const int b = blockIdx.x;
  const int l = threadIdx.x;
  const int j = l >> 2;
  const int k = l & 3;               // 0=i 1=f 2=g 3=o
  const int r = k * 16 + j;

  constexpr float LOG2E = 1.4426950408889634f;
  constexpr float K2    = -2.0f * LOG2E;       // cs = K2 * c
  const float sc = (k == 2) ? K2 : -LOG2E;

  half2_t w2[8];
  #pragma unroll
  for (int q = 0; q < 8; ++q) {
    w2[q][0] = (_Float16)(W_hh[r * 16 + 2 * q + 0] * sc);
    w2[q][1] = (_Float16)(W_hh[r * 16 + 2 * q + 1] * sc);
  }
  const float wx  = W_ih[r] * sc;
  const float wb  = (b_ih[r] + b_hh[r]) * sc;
  const float wfc = W_fc[j] * 0.25f;
  const float bfc = b_fc[0];

  const float* xb = x + (size_t)b * NT;
  float*       ob = out + (size_t)b * NT;

  float cs = 0.0f;                   // K2-scaled cell state
  int sp[8];                         // packed f16 h-pairs, wave-uniform
  #pragma unroll
  for (int q = 0; q < 8; ++q) sp[q] = 0;

  float xcur = xb[l];

  for (int blk = 0; blk < NT / 64; ++blk) {
    float xnext = 0.0f;
    if (blk + 1 < NT / 64) xnext = xb[(blk + 1) * 64 + l];  // prefetch
    float* mytile = &tile[blk & 1][0];

    #pragma unroll 16
    for (int tt = 0; tt < 64; ++tt) {
      const float sx    = rdlane(xcur, tt);        // uniform x_t (off-chain)
      const float xinit = fmaf(wx, sx, wb);        // off-chain
      // z = xinit + sum_q w2[q].h2[q]; 2 chains of depth 4 (R4 layout)
      float a0 = __builtin_amdgcn_fdot2(w2[0], h2_from_i(sp[0]), xinit, false);
      float a1 = __builtin_amdgcn_fdot2(w2[1], h2_from_i(sp[1]), 0.0f,  false);
      #pragma unroll
      for (int q = 2; q < 8; q += 2) {
        a0 = __builtin_amdgcn_fdot2(w2[q + 0], h2_from_i(sp[q + 0]), a0, false);
        a1 = __builtin_amdgcn_fdot2(w2[q + 1], h2_from_i(sp[q + 1]), a1, false);
      }
      const float z  = a0 + a1;
      const float e1 = vexp2(z);
      const float r1 = vrcp(1.0f + e1);            // sigma (i/f/o); sig(2zg) (g)
      // broadcast raw r1; g-affine applied post-broadcast (bit-identical)
      const float ii  = qbcast<0x00>(r1);
      const float ff  = qbcast<0x55>(r1);
      const float gr  = qbcast<0xAA>(r1);
      const float oo  = qbcast<0xFF>(r1);
      const float ggs = fmaf(gr, 2.0f * K2, -K2);  // = K2*tanh(zg), uniform
      const float oo2 = oo + oo;                   // off-chain
      cs = fmaf(ff, cs, ii * ggs);                 // K2-scaled cell update
      const float e2 = vexp2(cs);                  // = exp(-2c)
      const float r2 = vrcp(1.0f + e2);            // = sigma(2c)
      const float h  = fmaf(oo2, r2, -oo);         // = o * tanh(c)
      mytile[tt * 65 + l] = h * wfc;               // FC partial (off-chain)
      const float hn = dpp_shl4(h);                // (h_j, h_{j+1}) pack
      const int   hi = pack_f16(h, hn);
      #pragma unroll
      for (int q = 0; q < 8; ++q) sp[q] = rdlane_i(hi, 8 * q);
    }

    // Flush 64 outputs from this window's buffer; next window writes the
    // other buffer, so these reads can drift into its stall cycles.
    float s0 = bfc, s1 = 0.0f, s2 = 0.0f, s3 = 0.0f;
    #pragma unroll
    for (int i2 = 0; i2 < 64; i2 += 4) {
      s0 += mytile[l * 65 + i2 + 0];
      s1 += mytile[l * 65 + i2 + 1];
      s2 += mytile[l * 65 + i2 + 2];
      s3 += mytile[l * 65 + i2 + 3];
    }
    ob[blk * 64 + l] = (s0 + s1) + (s2 + s3);
    xcur = xnext;
  }
}

extern "C" void kernel_launch(void* const* d_in, const int* in_sizes, int n_in,
                              void* d_out, int out_size, void* d_ws, size_t ws_size,
                              hipStream_t stream) {
  const float* x    = (const float*)d_in[0];
  const float* W_ih = (const float*)d_in[1];
  const float* W_hh = (const float*)d_in[2];
  const float* b_ih = (const float*)d_in[3];
  const float* b_hh = (const float*)d_in[4];
  const float* W_fc = (const float*)d_in[5];
  const float* b_fc = (const float*)d_in[6];
  float* out = (float*)d_out;
  (void)in_sizes; (void)n_in; (void)out_size; (void)d_ws; (void)ws_size;
  lstm_fused<<<NB, 64, 0, stream>>>(x, W_ih, W_hh, b_ih, b_hh, W_fc, b_fc, out);
}